// Round 2
// baseline (388.049 us; speedup 1.0000x reference)
//
#include <hip/hip_runtime.h>
#include <math.h>

constexpr int BB = 4, CH = 512, NN = 4096, NHEADS = 4, NGROUPS = 32, HCH = 128;
constexpr float EPS = 1e-5f;
constexpr float SCALE = 0.08838834764831845f;  // 128^-0.5
constexpr float LOG2E = 1.4426950408889634f;
constexpr float QSCALE = SCALE * LOG2E;        // fold exp->exp2 domain into Q
constexpr float THR = 11.541560327111707f;     // 8 * log2(e)

typedef short bf16x8 __attribute__((ext_vector_type(8)));
typedef float f32x4 __attribute__((ext_vector_type(4)));
typedef float f32x16 __attribute__((ext_vector_type(16)));

__device__ __forceinline__ float bf2f(unsigned short u) {
    unsigned int x = ((unsigned int)u) << 16;
    float f; __builtin_memcpy(&f, &x, 4); return f;
}
__device__ __forceinline__ unsigned short f2bf(float f) {
    unsigned int x; __builtin_memcpy(&x, &f, 4);
    x += 0x7fff + ((x >> 16) & 1);          // RNE
    return (unsigned short)(x >> 16);
}
// RNE pack of 2 f32 -> 2 bf16 in one u32 (no builtin on gfx950; m240)
__device__ __forceinline__ unsigned int cvtpk(float lo, float hi) {
    unsigned int r;
    asm("v_cvt_pk_bf16_f32 %0, %1, %2" : "=v"(r) : "v"(lo), "v"(hi));
    return r;
}

// async global->LDS, 16B per lane; LDS dest = wave-uniform base + lane*16
__device__ __forceinline__ void gld16(const void* g, void* l) {
    __builtin_amdgcn_global_load_lds(
        (const __attribute__((address_space(1))) void*)g,
        (__attribute__((address_space(3))) void*)l, 16, 0, 0);
}

// ---------------------------------------------------------------------------
// GroupNorm statistics only: 128 blocks (b,g) -> stats[bg] = {mean, rstd}
// ---------------------------------------------------------------------------
__global__ __launch_bounds__(256) void gn_stats_kernel(
    const float* __restrict__ x, float2* __restrict__ stats)
{
    const int CPG = CH / NGROUPS;              // 16
    int bg = blockIdx.x;
    int b = bg / NGROUPS, g = bg % NGROUPS;
    const size_t base = ((size_t)b * CH + (size_t)g * CPG) * NN;
    const int total = CPG * NN;                // 65536
    const int total4 = total / 4;
    int tid = threadIdx.x;

    const float4* x4 = (const float4*)(x + base);
    float sum = 0.f, sumsq = 0.f;
    for (int i = tid; i < total4; i += 256) {
        float4 v = x4[i];
        sum   += v.x + v.y + v.z + v.w;
        sumsq += v.x*v.x + v.y*v.y + v.z*v.z + v.w*v.w;
    }
    for (int off = 32; off > 0; off >>= 1) {
        sum   += __shfl_down(sum, off);
        sumsq += __shfl_down(sumsq, off);
    }
    __shared__ float s_sum[4], s_sq[4];
    int wid = tid >> 6, lane = tid & 63;
    if (lane == 0) { s_sum[wid] = sum; s_sq[wid] = sumsq; }
    __syncthreads();
    if (tid == 0) {
        float ts = 0.f, tq = 0.f;
        for (int i = 0; i < 4; i++) { ts += s_sum[i]; tq += s_sq[i]; }
        float mean = ts / (float)total;
        float var  = tq / (float)total - mean * mean;
        stats[bg] = make_float2(mean, rsqrtf(var + EPS));
    }
}

// ---------------------------------------------------------------------------
// Weight convert fp32 -> bf16 (q rows pre-scaled by QSCALE = SCALE*log2e).
// ---------------------------------------------------------------------------
__global__ __launch_bounds__(256) void wconv_kernel(
    const float* __restrict__ qkv_w, const float* __restrict__ out_w,
    unsigned short* __restrict__ wq_bf, unsigned short* __restrict__ wo_bf)
{
    int i4 = blockIdx.x * 256 + threadIdx.x;   // float4 index
    if (i4 < 196608) {                         // 1536*512/4
        float4 w = ((const float4*)qkv_w)[i4];
        int row = i4 >> 7;
        float sc = (row < 512) ? QSCALE : 1.0f;
        ushort4 o = { f2bf(w.x * sc), f2bf(w.y * sc), f2bf(w.z * sc), f2bf(w.w * sc) };
        *(ushort4*)&wq_bf[(size_t)i4 * 4] = o;
    } else {
        int j4 = i4 - 196608;
        float4 w = ((const float4*)out_w)[j4];
        ushort4 o = { f2bf(w.x), f2bf(w.y), f2bf(w.z), f2bf(w.w) };
        *(ushort4*)&wo_bf[(size_t)j4 * 4] = o;
    }
}

// ---------------------------------------------------------------------------
// Transpose + inline GroupNorm apply:
//   xnT[b][n][c] = GN(x) bf16 ;  xT[b][n][c] = x bf16 (residual)
// ---------------------------------------------------------------------------
__global__ __launch_bounds__(256) void t1_kernel(
    const float* __restrict__ x, const float2* __restrict__ stats,
    const float* __restrict__ gamma, const float* __restrict__ beta,
    unsigned short* __restrict__ xnT, unsigned short* __restrict__ xT)
{
    __shared__ alignas(16) short Tn[64 * 80];
    __shared__ alignas(16) short Tr[64 * 80];
    int n0 = blockIdx.x * 64, c0 = blockIdx.y * 64, b = blockIdx.z;
    int tid = threadIdx.x;

    #pragma unroll
    for (int i = 0; i < 4; ++i) {
        int idx = tid + i * 256; int cl = idx >> 4, nq = idx & 15;
        int c = c0 + cl;
        float2 st = stats[b * NGROUPS + (c >> 4)];
        float gm = gamma[c], bt = beta[c];
        float4 f = *(const float4*)&x[((size_t)(b * CH + c)) * NN + n0 + nq * 4];
        float e0 = f.x, e1 = f.y, e2 = f.z, e3 = f.w;
        Tr[(nq * 4 + 0) * 80 + cl] = (short)f2bf(e0);
        Tr[(nq * 4 + 1) * 80 + cl] = (short)f2bf(e1);
        Tr[(nq * 4 + 2) * 80 + cl] = (short)f2bf(e2);
        Tr[(nq * 4 + 3) * 80 + cl] = (short)f2bf(e3);
        Tn[(nq * 4 + 0) * 80 + cl] = (short)f2bf((e0 - st.x) * st.y * gm + bt);
        Tn[(nq * 4 + 1) * 80 + cl] = (short)f2bf((e1 - st.x) * st.y * gm + bt);
        Tn[(nq * 4 + 2) * 80 + cl] = (short)f2bf((e2 - st.x) * st.y * gm + bt);
        Tn[(nq * 4 + 3) * 80 + cl] = (short)f2bf((e3 - st.x) * st.y * gm + bt);
    }
    __syncthreads();
    #pragma unroll
    for (int i = 0; i < 2; ++i) {
        int idx = tid + i * 256; int n = idx >> 3, ck = idx & 7;
        size_t gidx = ((size_t)(b * NN + n0 + n)) * CH + c0 + ck * 8;
        *(uint4*)&xnT[gidx] = *(uint4*)&Tn[n * 80 + ck * 8];
        *(uint4*)&xT[gidx]  = *(uint4*)&Tr[n * 80 + ck * 8];
    }
}

// ---------------------------------------------------------------------------
// MFMA GEMM: out[b][m][n] = A[m][:]·Bt[b][n][:] + bias
// ---------------------------------------------------------------------------
template<int MODE>
__global__ __launch_bounds__(256) void gemm_kernel(
    const unsigned short* __restrict__ A,    // [M][512] bf16
    const unsigned short* __restrict__ Bt,   // [B][4096][512] bf16
    const float* __restrict__ bias,          // [M]
    unsigned short* __restrict__ qT, unsigned short* __restrict__ kT,
    unsigned short* __restrict__ v, float* __restrict__ out)
{
    __shared__ alignas(16) short As[128 * 72];
    __shared__ alignas(16) short Bs[128 * 72];
    const int n0 = blockIdx.x * 128;
    const int m0 = blockIdx.y * 128;
    const int b  = blockIdx.z;
    const int tid = threadIdx.x;
    const int wid = tid >> 6, l = tid & 63, lr = l & 15, lk = l >> 4;
    const int wm = (wid & 1) * 64, wn = (wid >> 1) * 64;
    const unsigned short* Bb = Bt + (size_t)b * NN * CH;

    f32x4 acc[4][4];
    #pragma unroll
    for (int i = 0; i < 4; ++i)
        #pragma unroll
        for (int j = 0; j < 4; ++j) acc[i][j] = (f32x4){0.f, 0.f, 0.f, 0.f};

    uint4 areg[4], breg[4];
    #pragma unroll
    for (int i = 0; i < 4; ++i) {
        int idx = tid + i * 256; int r = idx >> 3, c = idx & 7;
        areg[i] = *(const uint4*)&A [((size_t)(m0 + r)) * CH + c * 8];
        breg[i] = *(const uint4*)&Bb[((size_t)(n0 + r)) * CH + c * 8];
    }

    for (int ks = 0; ks < 8; ++ks) {
        #pragma unroll
        for (int i = 0; i < 4; ++i) {
            int idx = tid + i * 256; int r = idx >> 3, c = idx & 7;
            *(uint4*)&As[r * 72 + c * 8] = areg[i];
            *(uint4*)&Bs[r * 72 + c * 8] = breg[i];
        }
        __syncthreads();
        if (ks < 7) {
            int k0 = (ks + 1) * 64;
            #pragma unroll
            for (int i = 0; i < 4; ++i) {
                int idx = tid + i * 256; int r = idx >> 3, c = idx & 7;
                areg[i] = *(const uint4*)&A [((size_t)(m0 + r)) * CH + k0 + c * 8];
                breg[i] = *(const uint4*)&Bb[((size_t)(n0 + r)) * CH + k0 + c * 8];
            }
        }
        #pragma unroll
        for (int kh = 0; kh < 2; ++kh) {
            bf16x8 af[4], bfr[4];
            #pragma unroll
            for (int t = 0; t < 4; ++t)
                af[t]  = *(const bf16x8*)&As[(wm + t * 16 + lr) * 72 + kh * 32 + lk * 8];
            #pragma unroll
            for (int t = 0; t < 4; ++t)
                bfr[t] = *(const bf16x8*)&Bs[(wn + t * 16 + lr) * 72 + kh * 32 + lk * 8];
            #pragma unroll
            for (int mt = 0; mt < 4; ++mt)
                #pragma unroll
                for (int nt = 0; nt < 4; ++nt)
                    acc[mt][nt] = __builtin_amdgcn_mfma_f32_16x16x32_bf16(
                        af[mt], bfr[nt], acc[mt][nt], 0, 0, 0);
        }
        __syncthreads();
    }

    #pragma unroll
    for (int mt = 0; mt < 4; ++mt) {
        int mbase = m0 + wm + mt * 16 + lk * 4;
        #pragma unroll
        for (int nt = 0; nt < 4; ++nt) {
            int n = n0 + wn + nt * 16 + lr;
            f32x4 vv = acc[mt][nt];
            if (MODE == 0) {
                if (m0 < 512) {          // Q -> qT[b][h][n][d]  (log2e-scaled)
                    int h = mbase >> 7, d = mbase & 127;
                    ushort4 o;
                    o.x = f2bf(vv[0] + bias[mbase + 0] * QSCALE);
                    o.y = f2bf(vv[1] + bias[mbase + 1] * QSCALE);
                    o.z = f2bf(vv[2] + bias[mbase + 2] * QSCALE);
                    o.w = f2bf(vv[3] + bias[mbase + 3] * QSCALE);
                    *(ushort4*)&qT[(((size_t)(b * 4 + h)) * NN + n) * 128 + d] = o;
                } else if (m0 < 1024) {  // K -> kT
                    int mm = mbase - 512;
                    int h = mm >> 7, d = mm & 127;
                    ushort4 o;
                    o.x = f2bf(vv[0] + bias[mbase + 0]);
                    o.y = f2bf(vv[1] + bias[mbase + 1]);
                    o.z = f2bf(vv[2] + bias[mbase + 2]);
                    o.w = f2bf(vv[3] + bias[mbase + 3]);
                    *(ushort4*)&kT[(((size_t)(b * 4 + h)) * NN + n) * 128 + d] = o;
                } else {                 // V -> v[d-major natural]
                    #pragma unroll
                    for (int j = 0; j < 4; ++j) {
                        int m = mbase + j;
                        v[((size_t)(b * 512 + (m - 1024))) * NN + n] =
                            f2bf(vv[j] + bias[m]);
                    }
                }
            } else {
                #pragma unroll
                for (int j = 0; j < 4; ++j) {
                    int m = mbase + j;
                    out[((size_t)(b * CH + m)) * NN + n] = vv[j] + bias[m];
                }
            }
        }
    }
}

// ---------------------------------------------------------------------------
// Flash attention, 32x32 MFMA + in-register P (T12).
// 4 waves x 32 q rows = 128 q/block, KVBLK=64, double-buffered K/V via
// global_load_lds (pre-swizzled source, linear LDS dest, swizzled reads).
// No P LDS: cvt_pk_bf16 + v_permlane32_swap_b32 redistribute P in-register.
// LDS = 64KB -> 2 blocks/CU (decoupled barriers).
// grid 512 blocks x 256 threads, XCD-swizzled.
// ---------------------------------------------------------------------------
__global__ __launch_bounds__(256, 2) void attn_kernel(
    const unsigned short* __restrict__ qT,  // [BH][N][128] (pre-scaled by SCALE*log2e)
    const unsigned short* __restrict__ kT,  // [BH][N][128]
    const unsigned short* __restrict__ vg,  // [BH*128][N]
    const unsigned short* __restrict__ xT,  // [B][N][512] residual bf16
    unsigned short* __restrict__ aoT)       // [B][N][512]
{
    __shared__ alignas(16) short Ks[2][64 * 128];   // 16KB/buf: [r][128] swz content
    __shared__ alignas(16) short Vs[2][128 * 64];   // 16KB/buf: [d][64]  swz content

    // bijective XCD swizzle: 512 wgs, 8 XCDs -> 64 consecutive wgs per XCD
    // (each XCD sees only 2 (b,h) panels -> K/V L2-resident)
    int lin_id = blockIdx.x + 32 * (blockIdx.y + 4 * blockIdx.z);
    int wg = (lin_id & 7) * 64 + (lin_id >> 3);
    const int n0 = (wg & 31) * 128;
    const int h  = (wg >> 5) & 3;
    const int b  = wg >> 7;

    const int bh = b * 4 + h;
    const int tid = threadIdx.x, wid = tid >> 6, l = tid & 63;
    const int lq = l & 31, hi = l >> 5;
    const int wq0 = wid * 32;
    const int swz = (l & 7) << 4;               // read-side XOR (bytes)
    const unsigned short* Qg = qT + (size_t)bh * NN * 128;
    const unsigned short* Kg = kT + (size_t)bh * NN * 128;
    const unsigned short* Vg = vg + (size_t)bh * 128 * NN;

    // staging geometry: 16 x 1KB chunks per tile per tensor, 4 chunks/wave.
    // chunk c, lane l covers LDS bytes c*1024 + l*16 (linear dest).
    int kr[4], kc[4], vd[4], vc[4], ch[4];
    #pragma unroll
    for (int i = 0; i < 4; ++i) {
        ch[i] = (wid * 4 + i) * 1024;
        int lin = ch[i] + l * 16;
        kr[i] = lin >> 8; kc[i] = ((lin >> 4) & 15) ^ (kr[i] & 7);
        vd[i] = lin >> 7; vc[i] = ((lin >> 4) & 7)  ^ (vd[i] & 7);
    }

    #define STAGE(buf, m0k) do {                                                   \
        _Pragma("unroll")                                                          \
        for (int i = 0; i < 4; ++i) {                                              \
            gld16(&Kg[(size_t)((m0k) + kr[i]) * 128 + kc[i] * 8],                  \
                  (char*)&Ks[buf][0] + ch[i]);                                     \
            gld16(&Vg[(size_t)vd[i] * NN + (m0k) + vc[i] * 8],                     \
                  (char*)&Vs[buf][0] + ch[i]);                                     \
        }                                                                          \
    } while (0)

    STAGE(0, 0);

    // ---- Q -> registers (overlaps staging latency) ----
    // B-operand frag for 32x32x16: lane holds Q[q = lq][k16 = hi*8 + j]
    bf16x8 qr[8];
    #pragma unroll
    for (int dk = 0; dk < 8; ++dk)
        qr[dk] = *(const bf16x8*)&Qg[((size_t)(n0 + wq0 + lq)) * 128 + dk * 16 + hi * 8];

    f32x16 ov[4];
    #pragma unroll
    for (int dt = 0; dt < 4; ++dt)
        #pragma unroll
        for (int r = 0; r < 16; ++r) ov[dt][r] = 0.f;
    float mrun = -1e30f, lrun = 0.f;

    __syncthreads();   // drains vmcnt -> tile 0 staged

    int cur = 0;
    for (int t = 0; t < 64; ++t) {
        if (t < 63) STAGE(cur ^ 1, (t + 1) * 64);   // in flight during compute

        const char* Kc = (const char*)&Ks[cur][0];
        const char* Vc = (const char*)&Vs[cur][0];

        // ---- QK^T (32x32x16): s[kt] col = q = lq, row = k-local
        //      k-local = (reg&3) + 8*(reg>>2) + 4*hi ----
        f32x16 s0, s1;
        #pragma unroll
        for (int r = 0; r < 16; ++r) { s0[r] = 0.f; s1[r] = 0.f; }
        __builtin_amdgcn_s_setprio(1);
        #pragma unroll
        for (int dk = 0; dk < 8; ++dk) {
            bf16x8 k0 = *(const bf16x8*)(Kc + (lq)      * 256 + ((dk * 32 + hi * 16) ^ swz));
            bf16x8 k1 = *(const bf16x8*)(Kc + (32 + lq) * 256 + ((dk * 32 + hi * 16) ^ swz));
            s0 = __builtin_amdgcn_mfma_f32_32x32x16_bf16(k0, qr[dk], s0, 0, 0, 0);
            s1 = __builtin_amdgcn_mfma_f32_32x32x16_bf16(k1, qr[dk], s1, 0, 0, 0);
        }
        __builtin_amdgcn_s_setprio(0);

        // ---- in-register online softmax (log2 domain; 1 q-row per lane pair) ----
        float m8[8];
        #pragma unroll
        for (int r = 0; r < 8; ++r)
            m8[r] = fmaxf(fmaxf(s0[r], s0[r + 8]), fmaxf(s1[r], s1[r + 8]));
        float ta = fmaxf(fmaxf(m8[0], m8[1]), m8[2]);
        float tb = fmaxf(fmaxf(m8[3], m8[4]), m8[5]);
        float tc = fmaxf(m8[6], m8[7]);
        float pm = fmaxf(fmaxf(ta, tb), tc);
        pm = fmaxf(pm, __shfl_xor(pm, 32));

        int defer = (pm - mrun) <= THR;
        if (!__all(defer)) {
            float mnew = fmaxf(mrun, pm);
            float corr = exp2f(mrun - mnew);
            lrun *= corr; mrun = mnew;
            #pragma unroll
            for (int dt = 0; dt < 4; ++dt)
                #pragma unroll
                for (int r = 0; r < 16; ++r) ov[dt][r] *= corr;
        }
        float ps = 0.f;
        #pragma unroll
        for (int r = 0; r < 16; ++r) { float e = exp2f(s0[r] - mrun); s0[r] = e; ps += e; }
        #pragma unroll
        for (int r = 0; r < 16; ++r) { float e = exp2f(s1[r] - mrun); s1[r] = e; ps += e; }
        ps += __shfl_xor(ps, 32);
        lrun += ps;

        // ---- P -> bf16 + in-register redistribution (T12) ----
        // u[2p+q] = bf16pair{ kv = kvbase + 8p + 4hi + 2q, +1 }
        unsigned int u0[8], u1[8];
        #pragma unroll
        for (int m = 0; m < 8; ++m) {
            u0[m] = cvtpk(s0[2 * m], s0[2 * m + 1]);
            u1[m] = cvtpk(s1[2 * m], s1[2 * m + 1]);
        }
        // pf[kt2]: B-frag, lane holds P[kv = kt2*16 + hi*8 + j][q = lq].
        // v_permlane32_swap_b32 a,b : a_hi <-> b_lo, so after swap(u[0],u[2]):
        //   a = [u0@lo | u2@lo] = word0 ; b = [u0@hi | u2@hi] = word2.
        bf16x8 pf[4];
        #pragma unroll
        for (int kt = 0; kt < 2; ++kt)
            #pragma unroll
            for (int hh = 0; hh < 2; ++hh) {
                const unsigned int* u = kt ? u1 : u0;
                unsigned int w0 = u[4*hh + 0], w2 = u[4*hh + 2];
                unsigned int w1 = u[4*hh + 1], w3 = u[4*hh + 3];
                asm("v_permlane32_swap_b32 %0, %1" : "+v"(w0), "+v"(w2));
                asm("v_permlane32_swap_b32 %0, %1" : "+v"(w1), "+v"(w3));
                unsigned int w[4] = { w0, w1, w2, w3 };
                bf16x8 p; __builtin_memcpy(&p, w, 16);
                pf[kt * 2 + hh] = p;
            }

        // ---- PV (32x32x16): ov[dt] += V^T-tile · P ----
        __builtin_amdgcn_s_setprio(1);
        #pragma unroll
        for (int dt = 0; dt < 4; ++dt)
            #pragma unroll
            for (int kt2 = 0; kt2 < 4; ++kt2) {
                bf16x8 vf = *(const bf16x8*)(Vc + (dt * 32 + lq) * 128 +
                                             ((kt2 * 32 + hi * 16) ^ swz));
                ov[dt] = __builtin_amdgcn_mfma_f32_32x32x16_bf16(vf, pf[kt2], ov[dt], 0, 0, 0);
            }
        __builtin_amdgcn_s_setprio(0);

        __syncthreads();   // drains vmcnt (t+1 staged) + guards buffer reuse
        cur ^= 1;
    }
    #undef STAGE

    // ---- epilogue: normalize, add residual, store aoT ----
    // ov[dt] row = d-local = (reg&3) + 8*(reg>>2) + 4*hi ; col = q = lq
    float linv = 1.0f / lrun;
    const int n = n0 + wq0 + lq;
    #pragma unroll
    for (int dt = 0; dt < 4; ++dt)
        #pragma unroll
        for (int m = 0; m < 4; ++m) {
            int d = dt * 32 + m * 8 + hi * 4;
            size_t gidx = ((size_t)(b * NN + n)) * CH + h * 128 + d;
            unsigned short xv[4];
            *(ushort4*)xv = *(const ushort4*)&xT[gidx];
            unsigned int w0 = cvtpk(ov[dt][4*m + 0] * linv + bf2f(xv[0]),
                                    ov[dt][4*m + 1] * linv + bf2f(xv[1]));
            unsigned int w1 = cvtpk(ov[dt][4*m + 2] * linv + bf2f(xv[2]),
                                    ov[dt][4*m + 3] * linv + bf2f(xv[3]));
            unsigned long long wv = (unsigned long long)w0 |
                                    ((unsigned long long)w1 << 32);
            *(unsigned long long*)&aoT[gidx] = wv;
        }
}

// ---------------------------------------------------------------------------
extern "C" void kernel_launch(void* const* d_in, const int* in_sizes, int n_in,
                              void* d_out, int out_size, void* d_ws, size_t ws_size,
                              hipStream_t stream) {
    const float* x      = (const float*)d_in[0];
    const float* gamma  = (const float*)d_in[1];
    const float* beta   = (const float*)d_in[2];
    const float* qkv_w  = (const float*)d_in[3];
    const float* qkv_b  = (const float*)d_in[4];
    const float* out_w  = (const float*)d_in[5];
    const float* out_b  = (const float*)d_in[6];
    float* out = (float*)d_out;

    char* ws = (char*)d_ws;
    const size_t SZ = (size_t)BB * CH * NN * 2;     // 16 MB per bf16 tensor
    unsigned short* xnT   = (unsigned short*)(ws);
    unsigned short* xT    = (unsigned short*)(ws + SZ);
    unsigned short* qT    = (unsigned short*)(ws + 2 * SZ);
    unsigned short* kT    = (unsigned short*)(ws + 3 * SZ);
    unsigned short* vbuf  = (unsigned short*)(ws + 4 * SZ);
    unsigned short* aoT   = (unsigned short*)(ws + 5 * SZ);
    unsigned short* wq_bf = (unsigned short*)(ws + 6 * SZ);
    unsigned short* wo_bf = (unsigned short*)(ws + 6 * SZ + (size_t)1536 * 512 * 2);
    float2* stats = (float2*)(ws + 6 * SZ + (size_t)2048 * 512 * 2);

    gn_stats_kernel<<<dim3(BB * NGROUPS), 256, 0, stream>>>(x, stats);
    wconv_kernel<<<dim3(1024), 256, 0, stream>>>(qkv_w, out_w, wq_bf, wo_bf);
    t1_kernel<<<dim3(NN / 64, CH / 64, BB), 256, 0, stream>>>(
        x, stats, gamma, beta, xnT, xT);
    gemm_kernel<0><<<dim3(NN / 128, 1536 / 128, BB), 256, 0, stream>>>(
        wq_bf, xnT, qkv_b, qT, kT, vbuf, nullptr);
    attn_kernel<<<dim3(NN / 128, NHEADS, BB), 256, 0, stream>>>(qT, kT, vbuf, xT, aoT);
    gemm_kernel<1><<<dim3(NN / 128, CH / 128, BB), 256, 0, stream>>>(
        wo_bf, aoT, out_b, nullptr, nullptr, nullptr, out);
}

// Round 3
// 355.721 us; speedup vs baseline: 1.0909x; 1.0909x over previous
//
#include <hip/hip_runtime.h>
#include <math.h>

constexpr int BB = 4, CH = 512, NN = 4096, NHEADS = 4, NGROUPS = 32, HCH = 128;
constexpr float EPS = 1e-5f;
constexpr float SCALE = 0.08838834764831845f;  // 128^-0.5
constexpr float LOG2E = 1.4426950408889634f;
constexpr float QSCALE = SCALE * LOG2E;        // fold exp->exp2 domain into Q
constexpr float THR = 11.541560327111707f;     // 8 * log2(e)

typedef short bf16x8 __attribute__((ext_vector_type(8)));
typedef float f32x4 __attribute__((ext_vector_type(4)));
typedef float f32x16 __attribute__((ext_vector_type(16)));

__device__ __forceinline__ float bf2f(unsigned short u) {
    unsigned int x = ((unsigned int)u) << 16;
    float f; __builtin_memcpy(&f, &x, 4); return f;
}
__device__ __forceinline__ unsigned short f2bf(float f) {
    unsigned int x; __builtin_memcpy(&x, &f, 4);
    x += 0x7fff + ((x >> 16) & 1);          // RNE
    return (unsigned short)(x >> 16);
}
// RNE pack of 2 f32 -> 2 bf16 in one u32 (no builtin on gfx950; m240)
__device__ __forceinline__ unsigned int cvtpk(float lo, float hi) {
    unsigned int r;
    asm("v_cvt_pk_bf16_f32 %0, %1, %2" : "=v"(r) : "v"(lo), "v"(hi));
    return r;
}
// raw 2^x (exp2f without fast-math lowers to a multi-instr ocml fixup path)
__device__ __forceinline__ float fexp2(float x) {
    float r; asm("v_exp_f32 %0, %1" : "=v"(r) : "v"(x)); return r;
}

// async global->LDS, 16B per lane; LDS dest = wave-uniform base + lane*16
__device__ __forceinline__ void gld16(const void* g, void* l) {
    __builtin_amdgcn_global_load_lds(
        (const __attribute__((address_space(1))) void*)g,
        (__attribute__((address_space(3))) void*)l, 16, 0, 0);
}

// ---------------------------------------------------------------------------
// GroupNorm statistics only: 128 blocks (b,g) -> stats[bg] = {mean, rstd}
// ---------------------------------------------------------------------------
__global__ __launch_bounds__(256) void gn_stats_kernel(
    const float* __restrict__ x, float2* __restrict__ stats)
{
    const int CPG = CH / NGROUPS;              // 16
    int bg = blockIdx.x;
    int b = bg / NGROUPS, g = bg % NGROUPS;
    const size_t base = ((size_t)b * CH + (size_t)g * CPG) * NN;
    const int total = CPG * NN;                // 65536
    const int total4 = total / 4;
    int tid = threadIdx.x;

    const float4* x4 = (const float4*)(x + base);
    float sum = 0.f, sumsq = 0.f;
    for (int i = tid; i < total4; i += 256) {
        float4 v = x4[i];
        sum   += v.x + v.y + v.z + v.w;
        sumsq += v.x*v.x + v.y*v.y + v.z*v.z + v.w*v.w;
    }
    for (int off = 32; off > 0; off >>= 1) {
        sum   += __shfl_down(sum, off);
        sumsq += __shfl_down(sumsq, off);
    }
    __shared__ float s_sum[4], s_sq[4];
    int wid = tid >> 6, lane = tid & 63;
    if (lane == 0) { s_sum[wid] = sum; s_sq[wid] = sumsq; }
    __syncthreads();
    if (tid == 0) {
        float ts = 0.f, tq = 0.f;
        for (int i = 0; i < 4; i++) { ts += s_sum[i]; tq += s_sq[i]; }
        float mean = ts / (float)total;
        float var  = tq / (float)total - mean * mean;
        stats[bg] = make_float2(mean, rsqrtf(var + EPS));
    }
}

// ---------------------------------------------------------------------------
// Weight convert fp32 -> bf16 (q rows pre-scaled by QSCALE = SCALE*log2e).
// ---------------------------------------------------------------------------
__global__ __launch_bounds__(256) void wconv_kernel(
    const float* __restrict__ qkv_w, const float* __restrict__ out_w,
    unsigned short* __restrict__ wq_bf, unsigned short* __restrict__ wo_bf)
{
    int i4 = blockIdx.x * 256 + threadIdx.x;   // float4 index
    if (i4 < 196608) {                         // 1536*512/4
        float4 w = ((const float4*)qkv_w)[i4];
        int row = i4 >> 7;
        float sc = (row < 512) ? QSCALE : 1.0f;
        ushort4 o = { f2bf(w.x * sc), f2bf(w.y * sc), f2bf(w.z * sc), f2bf(w.w * sc) };
        *(ushort4*)&wq_bf[(size_t)i4 * 4] = o;
    } else {
        int j4 = i4 - 196608;
        float4 w = ((const float4*)out_w)[j4];
        ushort4 o = { f2bf(w.x), f2bf(w.y), f2bf(w.z), f2bf(w.w) };
        *(ushort4*)&wo_bf[(size_t)j4 * 4] = o;
    }
}

// ---------------------------------------------------------------------------
// Transpose + inline GroupNorm apply:
//   xnT[b][n][c] = GN(x) bf16 ;  xT[b][n][c] = x bf16 (residual)
// ---------------------------------------------------------------------------
__global__ __launch_bounds__(256) void t1_kernel(
    const float* __restrict__ x, const float2* __restrict__ stats,
    const float* __restrict__ gamma, const float* __restrict__ beta,
    unsigned short* __restrict__ xnT, unsigned short* __restrict__ xT)
{
    __shared__ alignas(16) short Tn[64 * 80];
    __shared__ alignas(16) short Tr[64 * 80];
    int n0 = blockIdx.x * 64, c0 = blockIdx.y * 64, b = blockIdx.z;
    int tid = threadIdx.x;

    #pragma unroll
    for (int i = 0; i < 4; ++i) {
        int idx = tid + i * 256; int cl = idx >> 4, nq = idx & 15;
        int c = c0 + cl;
        float2 st = stats[b * NGROUPS + (c >> 4)];
        float gm = gamma[c], bt = beta[c];
        float4 f = *(const float4*)&x[((size_t)(b * CH + c)) * NN + n0 + nq * 4];
        float e0 = f.x, e1 = f.y, e2 = f.z, e3 = f.w;
        Tr[(nq * 4 + 0) * 80 + cl] = (short)f2bf(e0);
        Tr[(nq * 4 + 1) * 80 + cl] = (short)f2bf(e1);
        Tr[(nq * 4 + 2) * 80 + cl] = (short)f2bf(e2);
        Tr[(nq * 4 + 3) * 80 + cl] = (short)f2bf(e3);
        Tn[(nq * 4 + 0) * 80 + cl] = (short)f2bf((e0 - st.x) * st.y * gm + bt);
        Tn[(nq * 4 + 1) * 80 + cl] = (short)f2bf((e1 - st.x) * st.y * gm + bt);
        Tn[(nq * 4 + 2) * 80 + cl] = (short)f2bf((e2 - st.x) * st.y * gm + bt);
        Tn[(nq * 4 + 3) * 80 + cl] = (short)f2bf((e3 - st.x) * st.y * gm + bt);
    }
    __syncthreads();
    #pragma unroll
    for (int i = 0; i < 2; ++i) {
        int idx = tid + i * 256; int n = idx >> 3, ck = idx & 7;
        size_t gidx = ((size_t)(b * NN + n0 + n)) * CH + c0 + ck * 8;
        *(uint4*)&xnT[gidx] = *(uint4*)&Tn[n * 80 + ck * 8];
        *(uint4*)&xT[gidx]  = *(uint4*)&Tr[n * 80 + ck * 8];
    }
}

// ---------------------------------------------------------------------------
// MFMA GEMM: out[b][m][n] = A[m][:]·Bt[b][n][:] + bias
// MODE 0 epilogue: LDS-transpose -> fully coalesced 256B-row stores
// (direct scattered stores caused 6x write amplification: 282MB vs 48MB).
// ---------------------------------------------------------------------------
template<int MODE>
__global__ __launch_bounds__(256) void gemm_kernel(
    const unsigned short* __restrict__ A,    // [M][512] bf16
    const unsigned short* __restrict__ Bt,   // [B][4096][512] bf16
    const float* __restrict__ bias,          // [M]
    unsigned short* __restrict__ qT, unsigned short* __restrict__ kT,
    unsigned short* __restrict__ v, float* __restrict__ out)
{
    __shared__ alignas(16) short smem[2 * 128 * 72];   // 36KB
    short* As = smem;
    short* Bs = smem + 128 * 72;
    short* Es = smem;                                  // epilogue: 128*132 = 33.8KB
    const int n0 = blockIdx.x * 128;
    const int m0 = blockIdx.y * 128;
    const int b  = blockIdx.z;
    const int tid = threadIdx.x;
    const int wid = tid >> 6, l = tid & 63, lr = l & 15, lk = l >> 4;
    const int wm = (wid & 1) * 64, wn = (wid >> 1) * 64;
    const unsigned short* Bb = Bt + (size_t)b * NN * CH;

    f32x4 acc[4][4];
    #pragma unroll
    for (int i = 0; i < 4; ++i)
        #pragma unroll
        for (int j = 0; j < 4; ++j) acc[i][j] = (f32x4){0.f, 0.f, 0.f, 0.f};

    uint4 areg[4], breg[4];
    #pragma unroll
    for (int i = 0; i < 4; ++i) {
        int idx = tid + i * 256; int r = idx >> 3, c = idx & 7;
        areg[i] = *(const uint4*)&A [((size_t)(m0 + r)) * CH + c * 8];
        breg[i] = *(const uint4*)&Bb[((size_t)(n0 + r)) * CH + c * 8];
    }

    for (int ks = 0; ks < 8; ++ks) {
        #pragma unroll
        for (int i = 0; i < 4; ++i) {
            int idx = tid + i * 256; int r = idx >> 3, c = idx & 7;
            *(uint4*)&As[r * 72 + c * 8] = areg[i];
            *(uint4*)&Bs[r * 72 + c * 8] = breg[i];
        }
        __syncthreads();
        if (ks < 7) {
            int k0 = (ks + 1) * 64;
            #pragma unroll
            for (int i = 0; i < 4; ++i) {
                int idx = tid + i * 256; int r = idx >> 3, c = idx & 7;
                areg[i] = *(const uint4*)&A [((size_t)(m0 + r)) * CH + k0 + c * 8];
                breg[i] = *(const uint4*)&Bb[((size_t)(n0 + r)) * CH + k0 + c * 8];
            }
        }
        #pragma unroll
        for (int kh = 0; kh < 2; ++kh) {
            bf16x8 af[4], bfr[4];
            #pragma unroll
            for (int t = 0; t < 4; ++t)
                af[t]  = *(const bf16x8*)&As[(wm + t * 16 + lr) * 72 + kh * 32 + lk * 8];
            #pragma unroll
            for (int t = 0; t < 4; ++t)
                bfr[t] = *(const bf16x8*)&Bs[(wn + t * 16 + lr) * 72 + kh * 32 + lk * 8];
            #pragma unroll
            for (int mt = 0; mt < 4; ++mt)
                #pragma unroll
                for (int nt = 0; nt < 4; ++nt)
                    acc[mt][nt] = __builtin_amdgcn_mfma_f32_16x16x32_bf16(
                        af[mt], bfr[nt], acc[mt][nt], 0, 0, 0);
        }
        __syncthreads();
    }

    if (MODE == 0) {
        const bool isV = (m0 >= 1024);
        // acc -> Es.  Q/K: Es[n_local][m_local] (stride 132); V: Es[m_local][n_local]
        #pragma unroll
        for (int mt = 0; mt < 4; ++mt) {
            int mbase = m0 + wm + mt * 16 + lk * 4;
            int ml = wm + mt * 16 + lk * 4;
            float bsc = (m0 < 512) ? QSCALE : 1.0f;
            #pragma unroll
            for (int nt = 0; nt < 4; ++nt) {
                int nl = wn + nt * 16 + lr;
                f32x4 vv = acc[mt][nt];
                if (!isV) {
                    ushort4 o;
                    o.x = f2bf(vv[0] + bias[mbase + 0] * bsc);
                    o.y = f2bf(vv[1] + bias[mbase + 1] * bsc);
                    o.z = f2bf(vv[2] + bias[mbase + 2] * bsc);
                    o.w = f2bf(vv[3] + bias[mbase + 3] * bsc);
                    *(ushort4*)&Es[nl * 132 + ml] = o;          // 8B-aligned (132%4==0, ml%4==0)
                } else {
                    #pragma unroll
                    for (int j = 0; j < 4; ++j)
                        Es[(ml + j) * 132 + nl] = (short)f2bf(vv[j] + bias[mbase + j]);
                }
            }
        }
        __syncthreads();
        // coalesced stores: 256B contiguous per row
        int r16 = tid >> 4, c16 = tid & 15;
        if (!isV) {
            unsigned short* dst;
            if (m0 < 512) dst = qT + (((size_t)(b * 4 + (m0 >> 7))) * NN + n0) * 128;
            else          dst = kT + (((size_t)(b * 4 + ((m0 - 512) >> 7))) * NN + n0) * 128;
            #pragma unroll
            for (int p = 0; p < 8; ++p) {
                int nl = p * 16 + r16;
                uint4 w = *(const uint4*)&Es[nl * 132 + c16 * 8];
                *(uint4*)&dst[(size_t)nl * 128 + c16 * 8] = w;
            }
        } else {
            unsigned short* dst = v + ((size_t)(b * 512 + (m0 - 1024)) * NN) + n0;
            #pragma unroll
            for (int p = 0; p < 8; ++p) {
                int ml = p * 16 + r16;
                uint4 w = *(const uint4*)&Es[ml * 132 + c16 * 8];
                *(uint4*)&dst[(size_t)ml * NN + c16 * 8] = w;
            }
        }
    } else {
        #pragma unroll
        for (int mt = 0; mt < 4; ++mt) {
            int mbase = m0 + wm + mt * 16 + lk * 4;
            #pragma unroll
            for (int nt = 0; nt < 4; ++nt) {
                int n = n0 + wn + nt * 16 + lr;
                f32x4 vv = acc[mt][nt];
                #pragma unroll
                for (int j = 0; j < 4; ++j) {
                    int m = mbase + j;
                    out[((size_t)(b * CH + m)) * NN + n] = vv[j] + bias[m];
                }
            }
        }
    }
}

// ---------------------------------------------------------------------------
// Flash attention, 32x32 MFMA + in-register P (T12).
// 4 waves x 32 q rows = 128 q/block, KVBLK=64, double-buffered K/V via
// global_load_lds (pre-swizzled source, linear LDS dest, swizzled reads).
// 4-bit XOR swizzle (2-way/free): K rows 256B; V stored as 64 rows x 256B
// holding (d, d+64) half-pairs so the 4-bit swizzle applies.
// exp2 via raw v_exp_f32 (libm exp2f is a multi-instr fixup path).
// LDS = 64KB -> 2 blocks/CU. grid 512 x 256 thr, XCD-swizzled.
// ---------------------------------------------------------------------------
__global__ __launch_bounds__(256, 2) void attn_kernel(
    const unsigned short* __restrict__ qT,  // [BH][N][128] (pre-scaled by SCALE*log2e)
    const unsigned short* __restrict__ kT,  // [BH][N][128]
    const unsigned short* __restrict__ vg,  // [BH*128][N]
    const unsigned short* __restrict__ xT,  // [B][N][512] residual bf16
    unsigned short* __restrict__ aoT)       // [B][N][512]
{
    __shared__ alignas(16) short Ks[2][64 * 128];   // 16KB/buf: 64 rows x 256B
    __shared__ alignas(16) short Vs[2][64 * 128];   // 16KB/buf: 64 rows x 256B (d,d+64 pairs)

    // bijective XCD swizzle: 512 wgs, 8 XCDs -> 64 consecutive wgs per XCD
    int lin_id = blockIdx.x + 32 * (blockIdx.y + 4 * blockIdx.z);
    int wg = (lin_id & 7) * 64 + (lin_id >> 3);
    const int n0 = (wg & 31) * 128;
    const int h  = (wg >> 5) & 3;
    const int b  = wg >> 7;

    const int bh = b * 4 + h;
    const int tid = threadIdx.x, wid = tid >> 6, l = tid & 63;
    const int lq = l & 31, hi = l >> 5;
    const int wq0 = wid * 32;
    const int swz4 = (l & 15) << 4;             // read-side XOR, bits 4-7
    const unsigned short* Qg = qT + (size_t)bh * NN * 128;
    const unsigned short* Kg = kT + (size_t)bh * NN * 128;
    const unsigned short* Vg = vg + (size_t)bh * 128 * NN;

    // staging geometry: 16 x 1KB chunks per tile per tensor, 4 chunks/wave.
    // K: row kr (256B), phys slot s -> source col s ^ (kr&15)
    // V: row r holds d = r (slots L<8) and d = r+64 (L>=8); L = s ^ (r&15)
    int kr[4], kc[4], vdd[4], vcc[4], ch[4];
    #pragma unroll
    for (int i = 0; i < 4; ++i) {
        ch[i] = (wid * 4 + i) * 1024;
        int lin = ch[i] + l * 16;
        int r = lin >> 8, s = (lin >> 4) & 15;
        kr[i] = r; kc[i] = s ^ (r & 15);
        int L = s ^ (r & 15);
        vdd[i] = r + 64 * (L >> 3);
        vcc[i] = L & 7;
    }

    #define STAGE(buf, m0k) do {                                                   \
        _Pragma("unroll")                                                          \
        for (int i = 0; i < 4; ++i) {                                              \
            gld16(&Kg[(size_t)((m0k) + kr[i]) * 128 + kc[i] * 8],                  \
                  (char*)&Ks[buf][0] + ch[i]);                                     \
            gld16(&Vg[(size_t)vdd[i] * NN + (m0k) + vcc[i] * 8],                   \
                  (char*)&Vs[buf][0] + ch[i]);                                     \
        }                                                                          \
    } while (0)

    STAGE(0, 0);

    // ---- Q -> registers (overlaps staging latency) ----
    bf16x8 qr[8];
    #pragma unroll
    for (int dk = 0; dk < 8; ++dk)
        qr[dk] = *(const bf16x8*)&Qg[((size_t)(n0 + wq0 + lq)) * 128 + dk * 16 + hi * 8];

    f32x16 ov[4];
    #pragma unroll
    for (int dt = 0; dt < 4; ++dt)
        #pragma unroll
        for (int r = 0; r < 16; ++r) ov[dt][r] = 0.f;
    float mrun = -1e30f, lrun = 0.f;

    __syncthreads();   // drains vmcnt -> tile 0 staged

    int cur = 0;
    for (int t = 0; t < 64; ++t) {
        if (t < 63) STAGE(cur ^ 1, (t + 1) * 64);   // in flight during compute

        const char* Kc = (const char*)&Ks[cur][0];
        const char* Vc = (const char*)&Vs[cur][0];

        // ---- QK^T (32x32x16): col = q = lq, row k-local = (reg&3)+8*(reg>>2)+4*hi
        f32x16 s0, s1;
        #pragma unroll
        for (int r = 0; r < 16; ++r) { s0[r] = 0.f; s1[r] = 0.f; }
        __builtin_amdgcn_s_setprio(1);
        #pragma unroll
        for (int dk = 0; dk < 8; ++dk) {
            bf16x8 k0 = *(const bf16x8*)(Kc + (lq)      * 256 + ((dk * 32 + hi * 16) ^ swz4));
            bf16x8 k1 = *(const bf16x8*)(Kc + (32 + lq) * 256 + ((dk * 32 + hi * 16) ^ swz4));
            s0 = __builtin_amdgcn_mfma_f32_32x32x16_bf16(k0, qr[dk], s0, 0, 0, 0);
            s1 = __builtin_amdgcn_mfma_f32_32x32x16_bf16(k1, qr[dk], s1, 0, 0, 0);
        }
        __builtin_amdgcn_s_setprio(0);

        // ---- in-register online softmax (log2 domain) ----
        float m8[8];
        #pragma unroll
        for (int r = 0; r < 8; ++r)
            m8[r] = fmaxf(fmaxf(s0[r], s0[r + 8]), fmaxf(s1[r], s1[r + 8]));
        float t0 = fmaxf(fmaxf(m8[0], m8[1]), m8[2]);
        float t1_ = fmaxf(fmaxf(m8[3], m8[4]), m8[5]);
        float t2 = fmaxf(fmaxf(m8[6], m8[7]), t0);
        float pm = fmaxf(t1_, t2);
        pm = fmaxf(pm, __shfl_xor(pm, 32));

        int defer = (pm - mrun) <= THR;
        if (!__all(defer)) {
            float mnew = fmaxf(mrun, pm);
            float corr = fexp2(mrun - mnew);
            lrun *= corr; mrun = mnew;
            #pragma unroll
            for (int dt = 0; dt < 4; ++dt)
                #pragma unroll
                for (int r = 0; r < 16; ++r) ov[dt][r] *= corr;
        }
        float ps = 0.f;
        #pragma unroll
        for (int r = 0; r < 16; ++r) { float e = fexp2(s0[r] - mrun); s0[r] = e; ps += e; }
        #pragma unroll
        for (int r = 0; r < 16; ++r) { float e = fexp2(s1[r] - mrun); s1[r] = e; ps += e; }
        ps += __shfl_xor(ps, 32);
        lrun += ps;

        // ---- P -> bf16 + in-register redistribution (T12) ----
        unsigned int u0[8], u1[8];
        #pragma unroll
        for (int m = 0; m < 8; ++m) {
            u0[m] = cvtpk(s0[2 * m], s0[2 * m + 1]);
            u1[m] = cvtpk(s1[2 * m], s1[2 * m + 1]);
        }
        bf16x8 pf[4];
        #pragma unroll
        for (int kt = 0; kt < 2; ++kt)
            #pragma unroll
            for (int hh = 0; hh < 2; ++hh) {
                const unsigned int* u = kt ? u1 : u0;
                unsigned int w0 = u[4*hh + 0], w2 = u[4*hh + 2];
                unsigned int w1 = u[4*hh + 1], w3 = u[4*hh + 3];
                asm("v_permlane32_swap_b32 %0, %1" : "+v"(w0), "+v"(w2));
                asm("v_permlane32_swap_b32 %0, %1" : "+v"(w1), "+v"(w3));
                unsigned int w[4] = { w0, w1, w2, w3 };
                bf16x8 p; __builtin_memcpy(&p, w, 16);
                pf[kt * 2 + hh] = p;
            }

        // ---- PV (32x32x16): ov[dt] += V^T-tile · P ----
        // d = dt*32+lq -> Vs row r=(dt&1)*32+lq, half hh=dt>>1, chunk kt2*2+hi
        __builtin_amdgcn_s_setprio(1);
        #pragma unroll
        for (int dt = 0; dt < 4; ++dt)
            #pragma unroll
            for (int kt2 = 0; kt2 < 4; ++kt2) {
                bf16x8 vf = *(const bf16x8*)(Vc + ((dt & 1) * 32 + lq) * 256 +
                                             ((((dt >> 1) * 8 + kt2 * 2 + hi) << 4) ^ swz4));
                ov[dt] = __builtin_amdgcn_mfma_f32_32x32x16_bf16(vf, pf[kt2], ov[dt], 0, 0, 0);
            }
        __builtin_amdgcn_s_setprio(0);

        __syncthreads();   // drains vmcnt (t+1 staged) + guards buffer reuse
        cur ^= 1;
    }
    #undef STAGE

    // ---- epilogue: normalize, add residual, store aoT ----
    float linv = 1.0f / lrun;
    const int n = n0 + wq0 + lq;
    #pragma unroll
    for (int dt = 0; dt < 4; ++dt)
        #pragma unroll
        for (int m = 0; m < 4; ++m) {
            int d = dt * 32 + m * 8 + hi * 4;
            size_t gidx = ((size_t)(b * NN + n)) * CH + h * 128 + d;
            unsigned short xv[4];
            *(ushort4*)xv = *(const ushort4*)&xT[gidx];
            unsigned int w0 = cvtpk(ov[dt][4*m + 0] * linv + bf2f(xv[0]),
                                    ov[dt][4*m + 1] * linv + bf2f(xv[1]));
            unsigned int w1 = cvtpk(ov[dt][4*m + 2] * linv + bf2f(xv[2]),
                                    ov[dt][4*m + 3] * linv + bf2f(xv[3]));
            unsigned long long wv = (unsigned long long)w0 |
                                    ((unsigned long long)w1 << 32);
            *(unsigned long long*)&aoT[gidx] = wv;
        }
}

// ---------------------------------------------------------------------------
extern "C" void kernel_launch(void* const* d_in, const int* in_sizes, int n_in,
                              void* d_out, int out_size, void* d_ws, size_t ws_size,
                              hipStream_t stream) {
    const float* x      = (const float*)d_in[0];
    const float* gamma  = (const float*)d_in[1];
    const float* beta   = (const float*)d_in[2];
    const float* qkv_w  = (const float*)d_in[3];
    const float* qkv_b  = (const float*)d_in[4];
    const float* out_w  = (const float*)d_in[5];
    const float* out_b  = (const float*)d_in[6];
    float* out = (float*)d_out;

    char* ws = (char*)d_ws;
    const size_t SZ = (size_t)BB * CH * NN * 2;     // 16 MB per bf16 tensor
    unsigned short* xnT   = (unsigned short*)(ws);
    unsigned short* xT    = (unsigned short*)(ws + SZ);
    unsigned short* qT    = (unsigned short*)(ws + 2 * SZ);
    unsigned short* kT    = (unsigned short*)(ws + 3 * SZ);
    unsigned short* vbuf  = (unsigned short*)(ws + 4 * SZ);
    unsigned short* aoT   = (unsigned short*)(ws + 5 * SZ);
    unsigned short* wq_bf = (unsigned short*)(ws + 6 * SZ);
    unsigned short* wo_bf = (unsigned short*)(ws + 6 * SZ + (size_t)1536 * 512 * 2);
    float2* stats = (float2*)(ws + 6 * SZ + (size_t)2048 * 512 * 2);

    gn_stats_kernel<<<dim3(BB * NGROUPS), 256, 0, stream>>>(x, stats);
    wconv_kernel<<<dim3(1024), 256, 0, stream>>>(qkv_w, out_w, wq_bf, wo_bf);
    t1_kernel<<<dim3(NN / 64, CH / 64, BB), 256, 0, stream>>>(
        x, stats, gamma, beta, xnT, xT);
    gemm_kernel<0><<<dim3(NN / 128, 1536 / 128, BB), 256, 0, stream>>>(
        wq_bf, xnT, qkv_b, qT, kT, vbuf, nullptr);
    attn_kernel<<<dim3(NN / 128, NHEADS, BB), 256, 0, stream>>>(qT, kT, vbuf, xT, aoT);
    gemm_kernel<1><<<dim3(NN / 128, CH / 128, BB), 256, 0, stream>>>(
        wo_bf, aoT, out_b, nullptr, nullptr, nullptr, out);
}